// Round 9
// baseline (564.287 us; speedup 1.0000x reference)
//
#include <hip/hip_runtime.h>
#include <hip/hip_cooperative_groups.h>

namespace cg = cooperative_groups;

// SlotElmanCell: T=1024, Bb=2, D=1024, S=64
//   decay = sigmoid(decay_logits)            [D,S]
//   h[t+1] = decay*h[t] + B*x[t]             [Bb,D,S]
//   out[t] = (h[t+1] . C) * silu(z[t])       [Bb,D]
// Outputs (concat flat): out [T,Bb,D] then h [T+1,Bb,D,S]  (f32)
//
// R9: fused cooperative kernel. 512 blocks x 1024 thr (all co-resident:
// 64KB LDS => exactly 2 blocks/CU). Phase A = pass1's local scans (4 per
// wave, ILP-interleaved). grid.sync(). Phase B = 4 generation-major tiles
// (gen j = segs 4j..4j+3 device-wide = R7's confirmed narrow write window),
// with grid.sync() between generations to stop window drift.
// Fallback: R8 two-kernel path if cooperative launch unsupported.

#define T_    1024
#define BB_   2
#define D_    1024
#define S_    64
#define SEG_  64              // steps per segment
#define NSEG_ (T_ / SEG_)     // 16
#define NCH_  (BB_ * D_)      // 2048 chains
#define STRD_ (BB_ * D_)      // x/z stride between timesteps
#define CHB_  16              // chains per block
#define FG_   16              // steps per flush group
#define WS_NEED_ ((size_t)NCH_ * NSEG_ * S_ * 4)   // 8 MB

// Barrier that does NOT drain vmcnt (LDS ordering only).
#define LDS_BARRIER() asm volatile("s_waitcnt lgkmcnt(0)\n\ts_barrier" ::: "memory")

// x + dpp_shifted(x); bound_ctrl=1 -> out-of-range sources read 0.
#define DPP_ADD(x, ctrl, rm) \
  ((x) + __int_as_float(__builtin_amdgcn_update_dpp( \
        0, __float_as_int(x), (ctrl), (rm), 0xf, true)))

__device__ __forceinline__ float readlane_f(float v, int lane) {
    return __int_as_float(__builtin_amdgcn_readlane(__float_as_int(v), lane));
}

__device__ __forceinline__ float sigmoidf_(float v) {
    return 1.0f / (1.0f + __expf(-v));
}

// ---------------- Fused cooperative kernel --------------------------------
__global__ __launch_bounds__(1024, 8) void slot_elman_fused(
    const float* __restrict__ x, const float* __restrict__ z,
    const float* __restrict__ h0, const float* __restrict__ dl,
    const float* __restrict__ Bm, const float* __restrict__ C,
    float* __restrict__ ws, float* __restrict__ out, float* __restrict__ h)
{
    __shared__ float stage[FG_ * CHB_ * S_];   // 64 KB -> 2 blocks/CU

    cg::grid_group grid = cg::this_grid();

    const int r    = blockIdx.x;                    // 0..511
    const int g    = r & 127;                       // chain group
    const int sr   = r >> 7;                        // seg sub-row 0..3
    const int w    = threadIdx.x >> 6;              // wave 0..15
    const int lane = threadIdx.x & 63;              // slot s
    const int bd   = g * CHB_ + w;
    const int d    = bd & (D_ - 1);
    const int ds   = d * S_ + lane;

    const float decay = sigmoidf_(dl[ds]);
    const float Bv    = Bm[ds];
    const float Cv    = C[lane];

    // decay^64 by repeated squaring
    float dk = decay * decay;
    dk = dk * dk; dk = dk * dk; dk = dk * dk; dk = dk * dk;
    const float d64 = dk * dk;

    // ---- Phase A: local scans (zero init) for this block's 4 tiles:
    // tile j -> seg = 4*j + sr. 4 independent chains -> 4-way ILP.
    {
        const float xg0 = x[(size_t)((4*0 + sr) * SEG_ + lane) * STRD_ + bd];
        const float xg1 = x[(size_t)((4*1 + sr) * SEG_ + lane) * STRD_ + bd];
        const float xg2 = x[(size_t)((4*2 + sr) * SEG_ + lane) * STRD_ + bd];
        const float xg3 = x[(size_t)((4*3 + sr) * SEG_ + lane) * STRD_ + bd];
        float h0l = 0.f, h1l = 0.f, h2l = 0.f, h3l = 0.f;
        #pragma unroll
        for (int i = 0; i < SEG_; ++i) {
            h0l = fmaf(decay, h0l, Bv * readlane_f(xg0, i));
            h1l = fmaf(decay, h1l, Bv * readlane_f(xg1, i));
            h2l = fmaf(decay, h2l, Bv * readlane_f(xg2, i));
            h3l = fmaf(decay, h3l, Bv * readlane_f(xg3, i));
        }
        float* wb = ws + (size_t)bd * NSEG_ * S_ + lane;
        wb[(size_t)(4*0 + sr) * S_] = h0l;
        wb[(size_t)(4*1 + sr) * S_] = h1l;
        wb[(size_t)(4*2 + sr) * S_] = h2l;
        wb[(size_t)(4*3 + sr) * S_] = h3l;
    }

    __threadfence();
    grid.sync();

    // ---- Phase B: 4 tiles, generation-major (gen j = segs 4j..4j+3).
    #pragma unroll
    for (int j = 0; j < 4; ++j) {
        const int seg = 4 * j + sr;

        // Gathers (issue early; x lines L2-warm from phase A)
        const float xgA = x[(size_t)(seg * SEG_ + lane) * STRD_ + bd];
        const float zgA = z[(size_t)(seg * SEG_ + lane) * STRD_ + bd];

        // Segment start state: h0 folded with previous segments' local sums.
        float hv = h0[(size_t)bd * S_ + lane];
        if (seg == 0)
            h[(size_t)bd * S_ + lane] = hv;         // h[0] slice

        const float* wp = ws + (size_t)bd * NSEG_ * S_ + lane;
        #pragma unroll
        for (int jj = 0; jj < NSEG_ - 1; ++jj) {
            const float lj  = wp[(size_t)jj * S_];
            const float wgt = (jj < seg) ? d64 : 1.0f;
            const float add = (jj < seg) ? lj  : 0.0f;
            hv = fmaf(wgt, hv, add);
        }

        const float sgv = zgA * sigmoidf_(zgA);     // silu, lane = t
        float outacc = 0.0f;

        for (int f = 0; f < SEG_ / FG_; ++f) {      // 4 groups of 16 steps
            #pragma unroll
            for (int li = 0; li < FG_; ++li) {
                const int i = f * FG_ + li;
                const float xs = readlane_f(xgA, i);

                hv = fmaf(decay, hv, Bv * xs);      // recurrence

                // Stage h row: [li][chain w][slot]
                stage[(li * CHB_ + w) * S_ + lane] = hv;

                // Wave-wide sum of hv*Cv via DPP (pure VALU)
                float p = hv * Cv;
                p = DPP_ADD(p, 0x111, 0xf);  // row_shr:1
                p = DPP_ADD(p, 0x112, 0xf);  // row_shr:2
                p = DPP_ADD(p, 0x114, 0xf);  // row_shr:4
                p = DPP_ADD(p, 0x118, 0xf);  // row_shr:8
                p = DPP_ADD(p, 0x142, 0xa);  // row_bcast:15
                p = DPP_ADD(p, 0x143, 0xc);  // row_bcast:31 -> lane63

                const float ov = p * readlane_f(sgv, i);
                const float bc = readlane_f(ov, 63);
                outacc = (lane == i) ? bc : outacc;
            }

            LDS_BARRIER();   // stage writes visible; stores NOT drained

            // Flush: wave w -> t-slice f*16+w, ONE contiguous 4KB chunk
            {
                const int t1 = seg * SEG_ + f * FG_ + w + 1;
                const float4* src = (const float4*)&stage[w * CHB_ * S_];
                float4* dst = (float4*)&h[((size_t)t1 * NCH_ + (size_t)g * CHB_) * S_];
                dst[lane]       = src[lane];
                dst[lane + 64]  = src[lane + 64];
                dst[lane + 128] = src[lane + 128];
                dst[lane + 192] = src[lane + 192];
            }

            LDS_BARRIER();   // stage reads done; safe to overwrite
        }

        // out staging: [t-local][chain] with pad-17 stride
        stage[lane * 17 + w] = outacc;
        LDS_BARRIER();
        {
            const int tl = threadIdx.x >> 4;        // 0..63
            const int c  = threadIdx.x & 15;        // chain in group
            out[(size_t)(seg * SEG_ + tl) * STRD_ + (size_t)g * CHB_ + c] =
                stage[tl * 17 + c];
        }
        LDS_BARRIER();       // protect stage reuse by next tile

        if (j < 3) grid.sync();   // re-align the generation window
    }
}

// ---------------- Fallback pass1/pass2 (R8, proven 125.7us) ---------------
__global__ __launch_bounds__(256, 8) void slot_elman_pass1(
    const float* __restrict__ x, const float* __restrict__ dl,
    const float* __restrict__ Bm, float* __restrict__ ws)
{
    const int wave = blockIdx.x * (blockDim.x >> 6) + (threadIdx.x >> 6);
    const int lane = threadIdx.x & 63;
    const int bd   = wave & (NCH_ - 1);
    const int seg  = wave >> 11;
    const int d    = bd & (D_ - 1);
    const int ds   = d * S_ + lane;

    const float decay = sigmoidf_(dl[ds]);
    const float Bv    = Bm[ds];

    const float xg = x[(size_t)(seg * SEG_ + lane) * STRD_ + bd];

    float hl = 0.0f;
    #pragma unroll
    for (int i = 0; i < SEG_; ++i)
        hl = fmaf(decay, hl, Bv * readlane_f(xg, i));

    ws[(size_t)(bd * NSEG_ + seg) * S_ + lane] = hl;
}

__global__ __launch_bounds__(1024, 8) void slot_elman_pass2(
    const float* __restrict__ x, const float* __restrict__ z,
    const float* __restrict__ h0, const float* __restrict__ dl,
    const float* __restrict__ Bm, const float* __restrict__ C,
    const float* __restrict__ ws,
    float* __restrict__ out, float* __restrict__ h)
{
    __shared__ float stage[FG_ * CHB_ * S_];

    const int bid = blockIdx.x;
    const int seg = bid >> 7;
    const int g   = bid & 127;

    const int w    = threadIdx.x >> 6;
    const int lane = threadIdx.x & 63;
    const int bd   = g * CHB_ + w;
    const int d    = bd & (D_ - 1);
    const int ds   = d * S_ + lane;

    const float decay = sigmoidf_(dl[ds]);
    const float Bv    = Bm[ds];
    const float Cv    = C[lane];

    float dk = decay * decay;
    dk = dk * dk; dk = dk * dk; dk = dk * dk; dk = dk * dk;
    const float d64 = dk * dk;

    float hv = h0[(size_t)bd * S_ + lane];
    if (seg == 0)
        h[(size_t)bd * S_ + lane] = hv;

    const float* wp = ws + (size_t)bd * NSEG_ * S_ + lane;
    #pragma unroll
    for (int jj = 0; jj < NSEG_ - 1; ++jj) {
        const float lj  = wp[(size_t)jj * S_];
        const float wgt = (jj < seg) ? d64 : 1.0f;
        const float add = (jj < seg) ? lj  : 0.0f;
        hv = fmaf(wgt, hv, add);
    }

    const float xgA = x[(size_t)(seg * SEG_ + lane) * STRD_ + bd];
    const float zgA = z[(size_t)(seg * SEG_ + lane) * STRD_ + bd];
    const float sgv = zgA * sigmoidf_(zgA);

    float outacc = 0.0f;

    for (int f = 0; f < SEG_ / FG_; ++f) {
        #pragma unroll
        for (int li = 0; li < FG_; ++li) {
            const int i = f * FG_ + li;
            const float xs = readlane_f(xgA, i);

            hv = fmaf(decay, hv, Bv * xs);
            stage[(li * CHB_ + w) * S_ + lane] = hv;

            float p = hv * Cv;
            p = DPP_ADD(p, 0x111, 0xf);
            p = DPP_ADD(p, 0x112, 0xf);
            p = DPP_ADD(p, 0x114, 0xf);
            p = DPP_ADD(p, 0x118, 0xf);
            p = DPP_ADD(p, 0x142, 0xa);
            p = DPP_ADD(p, 0x143, 0xc);

            const float ov = p * readlane_f(sgv, i);
            const float bc = readlane_f(ov, 63);
            outacc = (lane == i) ? bc : outacc;
        }

        LDS_BARRIER();
        {
            const int t1 = seg * SEG_ + f * FG_ + w + 1;
            const float4* src = (const float4*)&stage[w * CHB_ * S_];
            float4* dst = (float4*)&h[((size_t)t1 * NCH_ + (size_t)g * CHB_) * S_];
            dst[lane]       = src[lane];
            dst[lane + 64]  = src[lane + 64];
            dst[lane + 128] = src[lane + 128];
            dst[lane + 192] = src[lane + 192];
        }
        LDS_BARRIER();
    }

    stage[lane * 17 + w] = outacc;
    LDS_BARRIER();
    {
        const int tl = threadIdx.x >> 4;
        const int c  = threadIdx.x & 15;
        out[(size_t)(seg * SEG_ + tl) * STRD_ + (size_t)g * CHB_ + c] =
            stage[tl * 17 + c];
    }
}

// ---------------- Fallback (R4 single kernel) if ws too small -------------
__global__ __launch_bounds__(256, 2) void slot_elman_fallback(
    const float* __restrict__ x, const float* __restrict__ z,
    const float* __restrict__ h0, const float* __restrict__ dl,
    const float* __restrict__ Bm, const float* __restrict__ C,
    float* __restrict__ out, float* __restrict__ h)
{
    const int nb  = gridDim.x;
    const int cpx = nb >> 3;
    const int bid = blockIdx.x;
    const int swz = (bid & 7) * cpx + (bid >> 3);

    const int wave = swz * (blockDim.x >> 6) + (threadIdx.x >> 6);
    const int lane = threadIdx.x & 63;
    const int bd = wave & (NCH_ - 1);
    const int d  = bd & (D_ - 1);
    const int ds = d * S_ + lane;

    const float decay = sigmoidf_(dl[ds]);
    const float Bv    = Bm[ds];
    const float Cv    = C[lane];

    float hv = h0[(size_t)bd * S_ + lane];
    h[(size_t)bd * S_ + lane] = hv;

    const float* xg_p = x + (size_t)lane * STRD_ + bd;
    const float* zg_p = z + (size_t)lane * STRD_ + bd;
    float*       hp = h + (size_t)(NCH_ * S_) + (size_t)bd * S_ + lane;
    float*       op = out + (size_t)lane * STRD_ + bd;

    float xgA = xg_p[0];
    float zgA = zg_p[0];

    for (int blk = 0; blk < NSEG_; ++blk) {
        const int tb = blk * SEG_;
        const int tbn = (blk + 1 < NSEG_) ? (tb + SEG_) : tb;
        const float xgB = xg_p[(size_t)tbn * STRD_];
        const float zgB = zg_p[(size_t)tbn * STRD_];

        const float sgv = zgA * sigmoidf_(zgA);
        float outacc = 0.0f;

        #pragma unroll 8
        for (int i = 0; i < SEG_; ++i) {
            const float xs = readlane_f(xgA, i);
            hv = fmaf(decay, hv, Bv * xs);
            hp[(size_t)(tb + i) * (NCH_ * S_)] = hv;

            float p = hv * Cv;
            p = DPP_ADD(p, 0x111, 0xf);
            p = DPP_ADD(p, 0x112, 0xf);
            p = DPP_ADD(p, 0x114, 0xf);
            p = DPP_ADD(p, 0x118, 0xf);
            p = DPP_ADD(p, 0x142, 0xa);
            p = DPP_ADD(p, 0x143, 0xc);

            const float ov = p * readlane_f(sgv, i);
            const float bc = readlane_f(ov, 63);
            outacc = (lane == i) ? bc : outacc;
        }
        op[(size_t)tb * STRD_] = outacc;
        xgA = xgB; zgA = zgB;
    }
}

extern "C" void kernel_launch(void* const* d_in, const int* in_sizes, int n_in,
                              void* d_out, int out_size, void* d_ws, size_t ws_size,
                              hipStream_t stream) {
    const float* x  = (const float*)d_in[0];   // [T,Bb,D]
    const float* z  = (const float*)d_in[1];   // [T,Bb,D]
    const float* h0 = (const float*)d_in[2];   // [Bb,D,S]
    const float* dl = (const float*)d_in[3];   // [D,S]
    const float* Bm = (const float*)d_in[4];   // [D,S]
    const float* C  = (const float*)d_in[5];   // [S]

    float* out = (float*)d_out;                            // [T,Bb,D]
    float* h   = (float*)d_out + (size_t)T_ * BB_ * D_;    // [T+1,Bb,D,S]

    if (ws_size >= WS_NEED_) {
        float* ws = (float*)d_ws;

        int coop = 0;
        (void)hipDeviceGetAttribute(&coop, hipDeviceAttributeCooperativeLaunch, 0);

        if (coop) {
            void* args[] = {(void*)&x, (void*)&z, (void*)&h0, (void*)&dl,
                            (void*)&Bm, (void*)&C, (void*)&ws, (void*)&out,
                            (void*)&h};
            hipError_t e = hipLaunchCooperativeKernel(
                (const void*)slot_elman_fused, dim3(512), dim3(1024),
                args, 0, stream);
            if (e == hipSuccess) return;
        }

        // Fallback: proven two-kernel path (R8)
        const int waves1 = NCH_ * NSEG_;
        const int grid1  = waves1 * 64 / 256;
        hipLaunchKernelGGL(slot_elman_pass1, dim3(grid1), dim3(256), 0, stream,
                           x, dl, Bm, ws);
        const int grid2  = (NCH_ / CHB_) * NSEG_;
        hipLaunchKernelGGL(slot_elman_pass2, dim3(grid2), dim3(1024), 0, stream,
                           x, z, h0, dl, Bm, C, ws, out, h);
    } else {
        const int waves = NCH_;
        const int grid  = waves * 64 / 256;
        hipLaunchKernelGGL(slot_elman_fallback, dim3(grid), dim3(256), 0, stream,
                           x, z, h0, dl, Bm, C, out, h);
    }
}

// Round 12
// 114.006 us; speedup vs baseline: 4.9496x; 4.9496x over previous
//
#include <hip/hip_runtime.h>

// SlotElmanCell: T=1024, Bb=2, D=1024, S=64
//   decay = sigmoid(decay_logits)            [D,S]
//   h[t+1] = decay*h[t] + B*x[t]             [Bb,D,S]
//   out[t] = (h[t+1] . C) * silu(z[t])       [Bb,D]
// Outputs (concat flat): out [T,Bb,D] then h [T+1,Bb,D,S]  (f32)
//
// R12 = R11 with the flush-offset bug fixed: the four 16B nt-stores per
// lane cover the wave's 4KB slice at FLOAT offsets 4*lane + {0,256,512,768}
// (64 float4 = 256 floats), not {0,1024,2048,3072}.
// h/out stores NON-TEMPORAL (write-once streams, no L2 allocate); ws
// stores regular (re-read by pass2).

#define T_    1024
#define BB_   2
#define D_    1024
#define S_    64
#define SEG_  64              // steps per segment
#define NSEG_ (T_ / SEG_)     // 16
#define NCH_  (BB_ * D_)      // 2048 chains
#define STRD_ (BB_ * D_)      // x/z stride between timesteps
#define CHB_  16              // chains per pass2 block
#define FG_   16              // steps per flush group
#define WS_NEED_ ((size_t)NCH_ * NSEG_ * S_ * 4)   // 8 MB

typedef float f32x4 __attribute__((ext_vector_type(4)));

// Barrier that does NOT drain vmcnt (LDS ordering only).
#define LDS_BARRIER() asm volatile("s_waitcnt lgkmcnt(0)\n\ts_barrier" ::: "memory")

// x + dpp_shifted(x); bound_ctrl=1 -> out-of-range sources read 0.
#define DPP_ADD(x, ctrl, rm) \
  ((x) + __int_as_float(__builtin_amdgcn_update_dpp( \
        0, __float_as_int(x), (ctrl), (rm), 0xf, true)))

__device__ __forceinline__ float readlane_f(float v, int lane) {
    return __int_as_float(__builtin_amdgcn_readlane(__float_as_int(v), lane));
}

__device__ __forceinline__ float sigmoidf_(float v) {
    return 1.0f / (1.0f + __expf(-v));
}

__device__ __forceinline__ void nt_store4(float* p, f32x4 v) {
    __builtin_nontemporal_store(v, (f32x4*)p);
}
__device__ __forceinline__ void nt_store1(float* p, float v) {
    __builtin_nontemporal_store(v, p);
}

// ---------------- Pass 1: per-segment local scans (zero init) -------------
__global__ __launch_bounds__(256, 8) void slot_elman_pass1(
    const float* __restrict__ x, const float* __restrict__ dl,
    const float* __restrict__ Bm, float* __restrict__ ws)
{
    const int wave = blockIdx.x * (blockDim.x >> 6) + (threadIdx.x >> 6);
    const int lane = threadIdx.x & 63;
    const int bd   = wave & (NCH_ - 1);     // chain
    const int seg  = wave >> 11;            // segment
    const int d    = bd & (D_ - 1);
    const int ds   = d * S_ + lane;

    const float decay = sigmoidf_(dl[ds]);
    const float Bv    = Bm[ds];

    const float xg = x[(size_t)(seg * SEG_ + lane) * STRD_ + bd];

    float hl = 0.0f;
    #pragma unroll
    for (int i = 0; i < SEG_; ++i)
        hl = fmaf(decay, hl, Bv * readlane_f(xg, i));

    ws[(size_t)(bd * NSEG_ + seg) * S_ + lane] = hl;   // regular store (re-read)
}

// ---------------- Pass 2: fold start state, scan, staged writes -----------
__global__ __launch_bounds__(1024, 8) void slot_elman_pass2(
    const float* __restrict__ x, const float* __restrict__ z,
    const float* __restrict__ h0, const float* __restrict__ dl,
    const float* __restrict__ Bm, const float* __restrict__ C,
    const float* __restrict__ ws,
    float* __restrict__ out, float* __restrict__ h)
{
    __shared__ float stage[FG_ * CHB_ * S_];   // 64 KB

    // Seg-major ordering (R7, confirmed): resident window = few segments
    // with all 128 chain-groups -> contiguous 512KB t-slice sweeps.
    const int bid = blockIdx.x;
    const int seg = bid >> 7;                       // 0..15
    const int g   = bid & 127;                      // chain group

    const int w    = threadIdx.x >> 6;              // wave 0..15
    const int lane = threadIdx.x & 63;              // slot s
    const int bd   = g * CHB_ + w;
    const int d    = bd & (D_ - 1);
    const int ds   = d * S_ + lane;

    const float decay = sigmoidf_(dl[ds]);
    const float Bv    = Bm[ds];
    const float Cv    = C[lane];

    // decay^64 by repeated squaring
    float dk = decay * decay;
    dk = dk * dk; dk = dk * dk; dk = dk * dk; dk = dk * dk;
    const float d64 = dk * dk;

    // Segment start state: h0 folded with previous segments' local sums.
    float hv = h0[(size_t)bd * S_ + lane];
    if (seg == 0)
        nt_store1(&h[(size_t)bd * S_ + lane], hv);  // h[0] slice

    const float* wp = ws + (size_t)bd * NSEG_ * S_ + lane;
    #pragma unroll
    for (int j = 0; j < NSEG_ - 1; ++j) {
        const float lj = wp[(size_t)j * S_];
        const float wgt = (j < seg) ? d64 : 1.0f;
        const float add = (j < seg) ? lj  : 0.0f;
        hv = fmaf(wgt, hv, add);
    }

    // Gathers: lane l covers t = seg*64 + l
    const float xgA = x[(size_t)(seg * SEG_ + lane) * STRD_ + bd];
    const float zgA = z[(size_t)(seg * SEG_ + lane) * STRD_ + bd];
    const float sgv = zgA * sigmoidf_(zgA);         // silu, lane = t

    float outacc = 0.0f;

    for (int f = 0; f < SEG_ / FG_; ++f) {          // 4 groups of 16 steps
        #pragma unroll
        for (int li = 0; li < FG_; ++li) {
            const int i = f * FG_ + li;             // segment-local step
            const float xs = readlane_f(xgA, i);

            hv = fmaf(decay, hv, Bv * xs);          // recurrence

            // Stage h row: [li][chain w][slot] -> 2-way bank alias (free)
            stage[(li * CHB_ + w) * S_ + lane] = hv;

            // Wave-wide sum of hv*Cv via DPP (pure VALU)
            float p = hv * Cv;
            p = DPP_ADD(p, 0x111, 0xf);  // row_shr:1
            p = DPP_ADD(p, 0x112, 0xf);  // row_shr:2
            p = DPP_ADD(p, 0x114, 0xf);  // row_shr:4
            p = DPP_ADD(p, 0x118, 0xf);  // row_shr:8
            p = DPP_ADD(p, 0x142, 0xa);  // row_bcast:15
            p = DPP_ADD(p, 0x143, 0xc);  // row_bcast:31 -> lane63 = total

            const float ov = p * readlane_f(sgv, i);
            const float bc = readlane_f(ov, 63);
            outacc = (lane == i) ? bc : outacc;     // deposit lane i
        }

        LDS_BARRIER();   // stage writes visible; global stores NOT drained

        // Flush: wave w takes t-slice li=w -> ONE contiguous 4KB chunk;
        // 128 same-seg blocks together cover the full 512KB t-slice.
        // Non-temporal: h is write-once, keep it out of L2.
        {
            const int t1 = seg * SEG_ + f * FG_ + w + 1;  // h slice index
            const float* src = &stage[w * CHB_ * S_];
            float* dst = &h[((size_t)t1 * NCH_ + (size_t)g * CHB_) * S_];
            const int o = lane * 4;                 // 64 lanes x 4 floats
            nt_store4(dst + o,       *(const f32x4*)(src + o));
            nt_store4(dst + o + 256, *(const f32x4*)(src + o + 256));
            nt_store4(dst + o + 512, *(const f32x4*)(src + o + 512));
            nt_store4(dst + o + 768, *(const f32x4*)(src + o + 768));
        }

        LDS_BARRIER();   // stage reads done; safe to overwrite next group
    }

    // out staging: [t-local][chain] with pad-17 stride (conflict-free)
    stage[lane * 17 + w] = outacc;
    LDS_BARRIER();
    {
        const int tl = threadIdx.x >> 4;            // 0..63
        const int c  = threadIdx.x & 15;            // chain in group
        nt_store1(&out[(size_t)(seg * SEG_ + tl) * STRD_ + (size_t)g * CHB_ + c],
                  stage[tl * 17 + c]);
    }
}

// ---------------- Fallback (R4 single kernel) if ws too small -------------
__global__ __launch_bounds__(256, 2) void slot_elman_fallback(
    const float* __restrict__ x, const float* __restrict__ z,
    const float* __restrict__ h0, const float* __restrict__ dl,
    const float* __restrict__ Bm, const float* __restrict__ C,
    float* __restrict__ out, float* __restrict__ h)
{
    const int nb  = gridDim.x;
    const int cpx = nb >> 3;
    const int bid = blockIdx.x;
    const int swz = (bid & 7) * cpx + (bid >> 3);

    const int wave = swz * (blockDim.x >> 6) + (threadIdx.x >> 6);
    const int lane = threadIdx.x & 63;
    const int bd = wave & (NCH_ - 1);
    const int d  = bd & (D_ - 1);
    const int ds = d * S_ + lane;

    const float decay = sigmoidf_(dl[ds]);
    const float Bv    = Bm[ds];
    const float Cv    = C[lane];

    float hv = h0[(size_t)bd * S_ + lane];
    h[(size_t)bd * S_ + lane] = hv;

    const float* xg_p = x + (size_t)lane * STRD_ + bd;
    const float* zg_p = z + (size_t)lane * STRD_ + bd;
    float*       hp = h + (size_t)(NCH_ * S_) + (size_t)bd * S_ + lane;
    float*       op = out + (size_t)lane * STRD_ + bd;

    float xgA = xg_p[0];
    float zgA = zg_p[0];

    for (int blk = 0; blk < NSEG_; ++blk) {
        const int tb = blk * SEG_;
        const int tbn = (blk + 1 < NSEG_) ? (tb + SEG_) : tb;
        const float xgB = xg_p[(size_t)tbn * STRD_];
        const float zgB = zg_p[(size_t)tbn * STRD_];

        const float sgv = zgA * sigmoidf_(zgA);
        float outacc = 0.0f;

        #pragma unroll 8
        for (int i = 0; i < SEG_; ++i) {
            const float xs = readlane_f(xgA, i);
            hv = fmaf(decay, hv, Bv * xs);
            hp[(size_t)(tb + i) * (NCH_ * S_)] = hv;

            float p = hv * Cv;
            p = DPP_ADD(p, 0x111, 0xf);
            p = DPP_ADD(p, 0x112, 0xf);
            p = DPP_ADD(p, 0x114, 0xf);
            p = DPP_ADD(p, 0x118, 0xf);
            p = DPP_ADD(p, 0x142, 0xa);
            p = DPP_ADD(p, 0x143, 0xc);

            const float ov = p * readlane_f(sgv, i);
            const float bc = readlane_f(ov, 63);
            outacc = (lane == i) ? bc : outacc;
        }
        op[(size_t)tb * STRD_] = outacc;
        xgA = xgB; zgA = zgB;
    }
}

extern "C" void kernel_launch(void* const* d_in, const int* in_sizes, int n_in,
                              void* d_out, int out_size, void* d_ws, size_t ws_size,
                              hipStream_t stream) {
    const float* x  = (const float*)d_in[0];   // [T,Bb,D]
    const float* z  = (const float*)d_in[1];   // [T,Bb,D]
    const float* h0 = (const float*)d_in[2];   // [Bb,D,S]
    const float* dl = (const float*)d_in[3];   // [D,S]
    const float* Bm = (const float*)d_in[4];   // [D,S]
    const float* C  = (const float*)d_in[5];   // [S]

    float* out = (float*)d_out;                            // [T,Bb,D]
    float* h   = (float*)d_out + (size_t)T_ * BB_ * D_;    // [T+1,Bb,D,S]

    if (ws_size >= WS_NEED_) {
        float* ws = (float*)d_ws;
        const int waves1 = NCH_ * NSEG_;          // 32768
        const int grid1  = waves1 * 64 / 256;     // 8192
        hipLaunchKernelGGL(slot_elman_pass1, dim3(grid1), dim3(256), 0, stream,
                           x, dl, Bm, ws);
        const int grid2  = (NCH_ / CHB_) * NSEG_; // 128 * 16 = 2048
        hipLaunchKernelGGL(slot_elman_pass2, dim3(grid2), dim3(1024), 0, stream,
                           x, z, h0, dl, Bm, C, ws, out, h);
    } else {
        const int waves = NCH_;                   // 2048
        const int grid  = waves * 64 / 256;       // 512
        hipLaunchKernelGGL(slot_elman_fallback, dim3(grid), dim3(256), 0, stream,
                           x, z, h0, dl, Bm, C, out, h);
    }
}